// Round 1
// baseline (678.124 us; speedup 1.0000x reference)
//
#include <hip/hip_runtime.h>
#include <math.h>

// DotProductAttention B=64,S=1024,D=64 fp32, bf16-MFMA flash attention.
// Round 3: concurrency attack. rocprof showed all pipes idle (Mfma 6%, VALU 26%,
// HBM 8%) with Occupancy 20% vs 50% static cap -> latency/imbalance bound.
//   1) Split-K 2-way: item = (b, qtile, half), grid 2048; partials (O~, m, l)
//      in workspace; LAST FINISHER of each pair combines (fence + atomic flag).
//      Halves the straggler (vl-dependent) tail; empty halves exit instantly.
//   2) Ps aliases Ks (+1 barrier): LDS 27.6 -> 18.4 KB -> 8 blocks/CU, so the
//      2048-block grid runs at 32 waves/CU (100% static) during the main phase.
//   3) __launch_bounds__(256,8): VGPR<=64 (was 60).
//   4) Pair blocks are bid and bid+64 -> same XCD -> combine reads partner's
//      partial from local L2.
// Fallback to the single-kernel version if ws_size < 34.6 MB.

#define BATCH 64
#define SEQ   1024
#define DIM   64
#define BQ    64           // queries per block (4 waves x 16)
#define BC    64           // keys per iteration
#define NKT   (SEQ / BC)   // 16
#define HALFT 8            // K-tiles per split-K item
#define LSTR  72           // LDS row stride in bf16 (144 B = 36 dwords === 4 mod 32)
#define QSCALE 0.18033688011112442f   // 0.125 * log2(e)
#define MASKED -1.0e6f

// workspace layout
#define WS_CNT_SZ  4096                         // 1024 x uint flags
#define WS_LM_OFF  4096
#define WS_LM_SZ   (2048 * 64 * 8)              // float2 (m,l) per query per item = 1 MB
#define WS_O_OFF   (WS_LM_OFF + WS_LM_SZ)       // 1052672
#define WS_O_SZ    (2048 * 4096 * 4)            // 32 MB of partial O
#define WS_NEEDED  ((size_t)WS_O_OFF + (size_t)WS_O_SZ)   // 34607104

typedef __attribute__((ext_vector_type(8))) short bf16x8;
typedef __attribute__((ext_vector_type(4))) float f32x4;

__device__ __forceinline__ uint pack2_trunc(float lo, float hi) {
    // [bf16(hi) : bf16(lo)] by byte-select (truncation) — one v_perm_b32
    return __builtin_amdgcn_perm(__float_as_uint(hi), __float_as_uint(lo), 0x07060302);
}
__device__ __forceinline__ ushort f2bf_rne(float x) {
    uint u = __float_as_uint(x);
    return (ushort)((u + 0x7fffu + ((u >> 16) & 1u)) >> 16);
}

// ---- combine: out[pair] = (O1*w1 + O2*w2) / (l1*w1 + l2*w2), exp2 domain ----
__device__ __forceinline__ void combine_pair(
    int pid, const int* __restrict__ valid_lens,
    const float2* __restrict__ lmbuf, const float* __restrict__ opart,
    float* __restrict__ out, int t)
{
    const int b  = pid & 63;
    const int qt = pid >> 6;
    const int vl = valid_lens[b];
    const bool has2 = !(vl != 0 && vl <= HALFT * BC);   // item2 empty iff 0 < vl <= 512
    const int i1 = pid * 2;
    const int qr = t >> 2;        // 64 query rows, 4 threads each
    const int c4 = t & 3;

    float2 ml1 = lmbuf[(size_t)i1 * 64 + qr];
    float w1, w2 = 0.f, denom;
    if (has2) {
        float2 ml2 = lmbuf[(size_t)(i1 + 1) * 64 + qr];
        float M = fmaxf(ml1.x, ml2.x);
        w1 = exp2f(ml1.x - M);
        w2 = exp2f(ml2.x - M);
        denom = ml1.y * w1 + ml2.y * w2;
    } else {
        w1 = 1.f;
        denom = ml1.y;
    }
    float inv = 1.f / denom;
    w1 *= inv; w2 *= inv;

    const float4* o1 = (const float4*)(opart + (size_t)i1 * (BQ * DIM));
    const float4* o2 = (const float4*)(opart + (size_t)(i1 + 1) * (BQ * DIM));
    float4* ob = (float4*)(out + ((size_t)b * SEQ + (size_t)qt * BQ) * DIM);
    #pragma unroll
    for (int j = 0; j < 4; j++) {
        int idx = qr * 16 + j * 4 + c4;   // lanes 0..3 cover 64 contiguous bytes
        float4 a = o1[idx];
        float4 r;
        r.x = a.x * w1; r.y = a.y * w1; r.z = a.z * w1; r.w = a.w * w1;
        if (has2) {
            float4 bb = o2[idx];
            r.x += bb.x * w2; r.y += bb.y * w2; r.z += bb.z * w2; r.w += bb.w * w2;
        }
        ob[idx] = r;
    }
}

__global__ __launch_bounds__(256, 8) void attn_mfma_splitk(
    const float* __restrict__ q, const float* __restrict__ k,
    const float* __restrict__ v, const int* __restrict__ valid_lens,
    float* __restrict__ out, uint* __restrict__ cnt,
    float2* __restrict__ lmbuf, float* __restrict__ opart)
{
    __shared__ ushort KPs[BC * LSTR];   // K tile; after barrier C, P tile (alias)
    __shared__ ushort Vt[DIM * LSTR];   // [d][key]
    __shared__ uint old_sh;

    const int t    = threadIdx.x;
    const int wave = t >> 6;
    const int wl   = t & 63;
    const int QD   = wl >> 4;          // quad 0..3
    const int li   = wl & 15;          // lane-in-quad 0..15
    // batch-major swizzle: all items of a batch land on the same XCD;
    // pair partner = bid + 64 -> also same XCD (64 % 8 == 0).
    const int b    = blockIdx.x & 63;
    const int rest = blockIdx.x >> 6;
    const int half = rest & 1;
    const int qt   = rest >> 1;
    const int q0   = qt * BQ;
    const int pid  = (qt << 6) | b;    // 0..1023
    const int item = pid * 2 + half;
    const int vl   = valid_lens[b];

    const size_t boff = (size_t)b * SEQ * DIM;

    const int it_full  = (vl == 0) ? NKT : ((vl + BC - 1) >> 6);
    const int it_begin = half * HALFT;
    const int it_end   = min(it_full, it_begin + HALFT);

    if (it_begin >= it_end) {
        // empty second half (0 < vl <= 512): partner holds everything
        if (t == 0) old_sh = atomicAdd(&cnt[pid], 1u);
        __syncthreads();
        if (old_sh == 1) {
            __threadfence();
            combine_pair(pid, valid_lens, lmbuf, opart, out, t);
        }
        return;
    }

    // ---- Q fragments straight into registers (B-operand), pre-scaled ----
    bf16x8 qb[2];
    {
        const float* qrow = q + boff + (size_t)(q0 + wave * 16 + li) * DIM + QD * 8;
        #pragma unroll
        for (int kc = 0; kc < 2; kc++) {
            float4 a = *(const float4*)(qrow + kc * 32);
            float4 c = *(const float4*)(qrow + kc * 32 + 4);
            union { bf16x8 v; ushort u[8]; } tmp;
            tmp.u[0] = f2bf_rne(a.x * QSCALE);
            tmp.u[1] = f2bf_rne(a.y * QSCALE);
            tmp.u[2] = f2bf_rne(a.z * QSCALE);
            tmp.u[3] = f2bf_rne(a.w * QSCALE);
            tmp.u[4] = f2bf_rne(c.x * QSCALE);
            tmp.u[5] = f2bf_rne(c.y * QSCALE);
            tmp.u[6] = f2bf_rne(c.z * QSCALE);
            tmp.u[7] = f2bf_rne(c.w * QSCALE);
            qb[kc] = tmp.v;
        }
    }

    // ---- prefetch registers ----
    float4 kf[4];          // K tile: 4 coalesced float4 per thread
    float  vf[2][8];       // V gather: (d = lane, 8 consecutive keys) x 2 slots

    auto load_tile = [&](int it) {
        const float4* kg = (const float4*)(k + boff + (size_t)it * BC * DIM);
        #pragma unroll
        for (int i = 0; i < 4; i++) kf[i] = kg[t + 256 * i];
        const float* vgf = v + boff + (size_t)it * BC * DIM;
        #pragma unroll
        for (int i = 0; i < 2; i++) {
            int slot = t + 256 * i;
            int d = slot & 63, ko = slot >> 6;
            #pragma unroll
            for (int j = 0; j < 8; j++)
                vf[i][j] = vgf[(size_t)(ko * 8 + j) * DIM + d];
        }
    };

    auto stage = [&]() {
        #pragma unroll
        for (int i = 0; i < 4; i++) {
            int idx = t + 256 * i;
            int row = idx >> 4, c4 = idx & 15;
            uint2 w;
            w.x = pack2_trunc(kf[i].x, kf[i].y);
            w.y = pack2_trunc(kf[i].z, kf[i].w);
            *(uint2*)&KPs[row * LSTR + c4 * 4] = w;
        }
        #pragma unroll
        for (int i = 0; i < 2; i++) {
            int slot = t + 256 * i;
            int d = slot & 63, ko = slot >> 6;
            uint4 w;
            w.x = pack2_trunc(vf[i][0], vf[i][1]);
            w.y = pack2_trunc(vf[i][2], vf[i][3]);
            w.z = pack2_trunc(vf[i][4], vf[i][5]);
            w.w = pack2_trunc(vf[i][6], vf[i][7]);
            *(uint4*)&Vt[d * LSTR + ko * 8] = w;   // b128, bank-uniform
        }
    };

    float m_run = -INFINITY, l_run = 0.f;
    f32x4 acc[4];
    #pragma unroll
    for (int dt = 0; dt < 4; dt++) acc[dt] = (f32x4){0.f, 0.f, 0.f, 0.f};

    load_tile(it_begin);

    for (int it = it_begin; it < it_end; it++) {
        __syncthreads();                  // (A) prior tile's P/V LDS reads done
        stage();
        if (it + 1 < it_end) load_tile(it + 1);   // in flight across compute
        __syncthreads();                  // (B) staging visible

        // ---- S^T = K x Q^T : rows = keys (QD*4+r), cols = queries (li) ----
        f32x4 sc[4];
        #pragma unroll
        for (int kt = 0; kt < 4; kt++) {
            bf16x8 ka0 = *(const bf16x8*)&KPs[(kt * 16 + li) * LSTR + QD * 8];
            bf16x8 ka1 = *(const bf16x8*)&KPs[(kt * 16 + li) * LSTR + 32 + QD * 8];
            f32x4 c = (f32x4){0.f, 0.f, 0.f, 0.f};
            c = __builtin_amdgcn_mfma_f32_16x16x32_bf16(ka0, qb[0], c, 0, 0, 0);
            c = __builtin_amdgcn_mfma_f32_16x16x32_bf16(ka1, qb[1], c, 0, 0, 0);
            sc[kt] = c;
        }

        __syncthreads();                  // (C) all waves done reading K -> region becomes P

        // ---- mask (only the boundary/invalid tiles pay per-element cost) ----
        const int kbase = it * BC;
        if (kbase + BC > vl) {
            #pragma unroll
            for (int kt = 0; kt < 4; kt++)
                #pragma unroll
                for (int r = 0; r < 4; r++) {
                    int key = kbase + kt * 16 + QD * 4 + r;
                    if (key >= vl) sc[kt][r] = MASKED;
                }
        }

        // ---- online softmax in exp2 domain (row = query = li) ----
        float mt = -INFINITY;
        #pragma unroll
        for (int kt = 0; kt < 4; kt++)
            #pragma unroll
            for (int r = 0; r < 4; r++) mt = fmaxf(mt, sc[kt][r]);
        mt = fmaxf(mt, __shfl_xor(mt, 16, 64));
        mt = fmaxf(mt, __shfl_xor(mt, 32, 64));
        float mn = fmaxf(m_run, mt);
        float alpha = exp2f(m_run - mn);   // -inf on first tile -> 0
        m_run = mn;

        float ls = 0.f;
        #pragma unroll
        for (int kt = 0; kt < 4; kt++) {
            float p0 = exp2f(sc[kt][0] - mn);
            float p1 = exp2f(sc[kt][1] - mn);
            float p2 = exp2f(sc[kt][2] - mn);
            float p3 = exp2f(sc[kt][3] - mn);
            ls += (p0 + p1) + (p2 + p3);
            uint2 w;
            w.x = pack2_trunc(p0, p1);
            w.y = pack2_trunc(p2, p3);
            *(uint2*)&KPs[(wave * 16 + li) * LSTR + kt * 16 + QD * 4] = w;
        }
        ls += __shfl_xor(ls, 16, 64);
        ls += __shfl_xor(ls, 32, 64);
        l_run = l_run * alpha + ls;

        // rescale O accumulator rows (row = QD*4+r holds query QD*4+r)
        float a0 = __shfl(alpha, QD * 4 + 0, 64);
        float a1 = __shfl(alpha, QD * 4 + 1, 64);
        float a2 = __shfl(alpha, QD * 4 + 2, 64);
        float a3 = __shfl(alpha, QD * 4 + 3, 64);
        #pragma unroll
        for (int dt = 0; dt < 4; dt++) {
            acc[dt][0] *= a0; acc[dt][1] *= a1;
            acc[dt][2] *= a2; acc[dt][3] *= a3;
        }

        // ---- PV: O += P x V (same-wave LDS round-trip for P; P rows wave-private) ----
        bf16x8 pa0 = *(const bf16x8*)&KPs[(wave * 16 + li) * LSTR + QD * 8];
        bf16x8 pa1 = *(const bf16x8*)&KPs[(wave * 16 + li) * LSTR + 32 + QD * 8];
        #pragma unroll
        for (int dt = 0; dt < 4; dt++) {
            bf16x8 vb0 = *(const bf16x8*)&Vt[(dt * 16 + li) * LSTR + QD * 8];
            bf16x8 vb1 = *(const bf16x8*)&Vt[(dt * 16 + li) * LSTR + 32 + QD * 8];
            acc[dt] = __builtin_amdgcn_mfma_f32_16x16x32_bf16(pa0, vb0, acc[dt], 0, 0, 0);
            acc[dt] = __builtin_amdgcn_mfma_f32_16x16x32_bf16(pa1, vb1, acc[dt], 0, 0, 0);
        }
    }

    // ---- epilogue: write UNNORMALIZED partial + (m,l), then flag ----
    if (QD == 0)
        lmbuf[(size_t)item * 64 + wave * 16 + li] = make_float2(m_run, l_run);

    {
        float* ob = opart + (size_t)item * (BQ * DIM);
        const int rbase = wave * 16 + QD * 4;
        #pragma unroll
        for (int dt = 0; dt < 4; dt++) {
            int col = dt * 16 + li;
            ob[(size_t)(rbase + 0) * DIM + col] = acc[dt][0];
            ob[(size_t)(rbase + 1) * DIM + col] = acc[dt][1];
            ob[(size_t)(rbase + 2) * DIM + col] = acc[dt][2];
            ob[(size_t)(rbase + 3) * DIM + col] = acc[dt][3];
        }
    }

    __threadfence();                       // release partials (device scope)
    if (t == 0) old_sh = atomicAdd(&cnt[pid], 1u);
    __syncthreads();
    if (old_sh == 1) {                     // last finisher combines
        __threadfence();                   // acquire partner's partials
        combine_pair(pid, valid_lens, lmbuf, opart, out, t);
    }
}

// ---------------- fallback (no/short workspace): previous verified kernel ----------------
__global__ __launch_bounds__(256, 4) void attn_mfma_flash2(
    const float* __restrict__ q, const float* __restrict__ k,
    const float* __restrict__ v, const int* __restrict__ valid_lens,
    float* __restrict__ out)
{
    __shared__ ushort Ks[BC * LSTR];   // [key][d]
    __shared__ ushort Vt[DIM * LSTR];  // [d][key]
    __shared__ ushort Ps[BQ * LSTR];   // [query][key], wave-private 16-row bands

    const int t    = threadIdx.x;
    const int wave = t >> 6;
    const int wl   = t & 63;
    const int QD   = wl >> 4;
    const int li   = wl & 15;
    const int b    = blockIdx.x & 63;
    const int q0   = (blockIdx.x >> 6) * BQ;
    const int vl   = valid_lens[b];

    const size_t boff = (size_t)b * SEQ * DIM;

    bf16x8 qb[2];
    {
        const float* qrow = q + boff + (size_t)(q0 + wave * 16 + li) * DIM + QD * 8;
        #pragma unroll
        for (int kc = 0; kc < 2; kc++) {
            float4 a = *(const float4*)(qrow + kc * 32);
            float4 c = *(const float4*)(qrow + kc * 32 + 4);
            union { bf16x8 v; ushort u[8]; } tmp;
            tmp.u[0] = f2bf_rne(a.x * QSCALE);
            tmp.u[1] = f2bf_rne(a.y * QSCALE);
            tmp.u[2] = f2bf_rne(a.z * QSCALE);
            tmp.u[3] = f2bf_rne(a.w * QSCALE);
            tmp.u[4] = f2bf_rne(c.x * QSCALE);
            tmp.u[5] = f2bf_rne(c.y * QSCALE);
            tmp.u[6] = f2bf_rne(c.z * QSCALE);
            tmp.u[7] = f2bf_rne(c.w * QSCALE);
            qb[kc] = tmp.v;
        }
    }

    const int it_max = (vl == 0) ? NKT : ((vl + BC - 1) >> 6);

    float4 kf[4];
    float  vf[2][8];

    auto load_tile = [&](int it) {
        const float4* kg = (const float4*)(k + boff + (size_t)it * BC * DIM);
        #pragma unroll
        for (int i = 0; i < 4; i++) kf[i] = kg[t + 256 * i];
        const float* vgf = v + boff + (size_t)it * BC * DIM;
        #pragma unroll
        for (int i = 0; i < 2; i++) {
            int slot = t + 256 * i;
            int d = slot & 63, ko = slot >> 6;
            #pragma unroll
            for (int j = 0; j < 8; j++)
                vf[i][j] = vgf[(size_t)(ko * 8 + j) * DIM + d];
        }
    };

    auto stage = [&]() {
        #pragma unroll
        for (int i = 0; i < 4; i++) {
            int idx = t + 256 * i;
            int row = idx >> 4, c4 = idx & 15;
            uint2 w;
            w.x = pack2_trunc(kf[i].x, kf[i].y);
            w.y = pack2_trunc(kf[i].z, kf[i].w);
            *(uint2*)&Ks[row * LSTR + c4 * 4] = w;
        }
        #pragma unroll
        for (int i = 0; i < 2; i++) {
            int slot = t + 256 * i;
            int d = slot & 63, ko = slot >> 6;
            uint4 w;
            w.x = pack2_trunc(vf[i][0], vf[i][1]);
            w.y = pack2_trunc(vf[i][2], vf[i][3]);
            w.z = pack2_trunc(vf[i][4], vf[i][5]);
            w.w = pack2_trunc(vf[i][6], vf[i][7]);
            *(uint4*)&Vt[d * LSTR + ko * 8] = w;
        }
    };

    float m_run = -INFINITY, l_run = 0.f;
    f32x4 acc[4];
    #pragma unroll
    for (int dt = 0; dt < 4; dt++) acc[dt] = (f32x4){0.f, 0.f, 0.f, 0.f};

    load_tile(0);

    for (int it = 0; it < it_max; it++) {
        __syncthreads();
        stage();
        if (it + 1 < it_max) load_tile(it + 1);
        __syncthreads();

        f32x4 sc[4];
        #pragma unroll
        for (int kt = 0; kt < 4; kt++) {
            bf16x8 ka0 = *(const bf16x8*)&Ks[(kt * 16 + li) * LSTR + QD * 8];
            bf16x8 ka1 = *(const bf16x8*)&Ks[(kt * 16 + li) * LSTR + 32 + QD * 8];
            f32x4 c = (f32x4){0.f, 0.f, 0.f, 0.f};
            c = __builtin_amdgcn_mfma_f32_16x16x32_bf16(ka0, qb[0], c, 0, 0, 0);
            c = __builtin_amdgcn_mfma_f32_16x16x32_bf16(ka1, qb[1], c, 0, 0, 0);
            sc[kt] = c;
        }

        const int kbase = it * BC;
        if (kbase + BC > vl) {
            #pragma unroll
            for (int kt = 0; kt < 4; kt++)
                #pragma unroll
                for (int r = 0; r < 4; r++) {
                    int key = kbase + kt * 16 + QD * 4 + r;
                    if (key >= vl) sc[kt][r] = MASKED;
                }
        }

        float mt = -INFINITY;
        #pragma unroll
        for (int kt = 0; kt < 4; kt++)
            #pragma unroll
            for (int r = 0; r < 4; r++) mt = fmaxf(mt, sc[kt][r]);
        mt = fmaxf(mt, __shfl_xor(mt, 16, 64));
        mt = fmaxf(mt, __shfl_xor(mt, 32, 64));
        float mn = fmaxf(m_run, mt);
        float alpha = exp2f(m_run - mn);
        m_run = mn;

        float ls = 0.f;
        #pragma unroll
        for (int kt = 0; kt < 4; kt++) {
            float p0 = exp2f(sc[kt][0] - mn);
            float p1 = exp2f(sc[kt][1] - mn);
            float p2 = exp2f(sc[kt][2] - mn);
            float p3 = exp2f(sc[kt][3] - mn);
            ls += (p0 + p1) + (p2 + p3);
            uint2 w;
            w.x = pack2_trunc(p0, p1);
            w.y = pack2_trunc(p2, p3);
            *(uint2*)&Ps[(wave * 16 + li) * LSTR + kt * 16 + QD * 4] = w;
        }
        ls += __shfl_xor(ls, 16, 64);
        ls += __shfl_xor(ls, 32, 64);
        l_run = l_run * alpha + ls;

        float a0 = __shfl(alpha, QD * 4 + 0, 64);
        float a1 = __shfl(alpha, QD * 4 + 1, 64);
        float a2 = __shfl(alpha, QD * 4 + 2, 64);
        float a3 = __shfl(alpha, QD * 4 + 3, 64);
        #pragma unroll
        for (int dt = 0; dt < 4; dt++) {
            acc[dt][0] *= a0; acc[dt][1] *= a1;
            acc[dt][2] *= a2; acc[dt][3] *= a3;
        }

        bf16x8 pa0 = *(const bf16x8*)&Ps[(wave * 16 + li) * LSTR + QD * 8];
        bf16x8 pa1 = *(const bf16x8*)&Ps[(wave * 16 + li) * LSTR + 32 + QD * 8];
        #pragma unroll
        for (int dt = 0; dt < 4; dt++) {
            bf16x8 vb0 = *(const bf16x8*)&Vt[(dt * 16 + li) * LSTR + QD * 8];
            bf16x8 vb1 = *(const bf16x8*)&Vt[(dt * 16 + li) * LSTR + 32 + QD * 8];
            acc[dt] = __builtin_amdgcn_mfma_f32_16x16x32_bf16(pa0, vb0, acc[dt], 0, 0, 0);
            acc[dt] = __builtin_amdgcn_mfma_f32_16x16x32_bf16(pa1, vb1, acc[dt], 0, 0, 0);
        }
    }

    float invl = 1.0f / l_run;
    float i0 = __shfl(invl, QD * 4 + 0, 64);
    float i1 = __shfl(invl, QD * 4 + 1, 64);
    float i2 = __shfl(invl, QD * 4 + 2, 64);
    float i3 = __shfl(invl, QD * 4 + 3, 64);
    float* ob = out + boff + (size_t)q0 * DIM;
    const int rbase = wave * 16 + QD * 4;
    #pragma unroll
    for (int dt = 0; dt < 4; dt++) {
        int col = dt * 16 + li;
        ob[(size_t)(rbase + 0) * DIM + col] = acc[dt][0] * i0;
        ob[(size_t)(rbase + 1) * DIM + col] = acc[dt][1] * i1;
        ob[(size_t)(rbase + 2) * DIM + col] = acc[dt][2] * i2;
        ob[(size_t)(rbase + 3) * DIM + col] = acc[dt][3] * i3;
    }
}

extern "C" void kernel_launch(void* const* d_in, const int* in_sizes, int n_in,
                              void* d_out, int out_size, void* d_ws, size_t ws_size,
                              hipStream_t stream) {
    const float* q = (const float*)d_in[0];
    const float* k = (const float*)d_in[1];
    const float* v = (const float*)d_in[2];
    const int* valid_lens = (const int*)d_in[3];
    float* out = (float*)d_out;

    if (d_ws != nullptr && ws_size >= WS_NEEDED) {
        // split-K path: zero the 1024 pair flags, then one kernel (combine inside)
        hipMemsetAsync(d_ws, 0, WS_CNT_SZ, stream);
        uint*   cnt   = (uint*)d_ws;
        float2* lmbuf = (float2*)((char*)d_ws + WS_LM_OFF);
        float*  opart = (float*)((char*)d_ws + WS_O_OFF);
        dim3 grid(BATCH * (SEQ / BQ) * 2);   // 2048 blocks
        attn_mfma_splitk<<<grid, dim3(256), 0, stream>>>(
            q, k, v, valid_lens, out, cnt, lmbuf, opart);
    } else {
        dim3 grid(BATCH * (SEQ / BQ));       // 1024 blocks
        attn_mfma_flash2<<<grid, dim3(256), 0, stream>>>(q, k, v, valid_lens, out);
    }
}

// Round 2
// 479.402 us; speedup vs baseline: 1.4145x; 1.4145x over previous
//
#include <hip/hip_runtime.h>
#include <math.h>

// DotProductAttention B=64,S=1024,D=64 fp32, bf16-MFMA flash attention.
// Round 4: fix round-3's register catastrophe. __launch_bounds__(256,8) forced
// the allocator to 32 VGPR -> full working-set spill (FETCH 238MB / WRITE 416MB
// of scratch, 617us). Revert to (256,4): this loop body compiles to ~60 VGPR
// with no spill; since 60 <= 64 the HW can still co-schedule 8 waves/SIMD, and
// LDS 18.9KB allows 8 blocks/CU. Split-K structure (proven correct in round 3)
// is unchanged:
//   - item = (b, qtile, half), grid 2048; partials (O~, m, l) in workspace;
//     last finisher of each pair combines (fence + atomic flag).
//   - Ps aliases Ks (+1 barrier): LDS 27.6 -> 18.4 KB.
//   - pair partner = bid + 64 -> same XCD -> combine reads partner from local L2.
// Fallback to the single-kernel version if ws_size < 34.6 MB.

#define BATCH 64
#define SEQ   1024
#define DIM   64
#define BQ    64           // queries per block (4 waves x 16)
#define BC    64           // keys per iteration
#define NKT   (SEQ / BC)   // 16
#define HALFT 8            // K-tiles per split-K item
#define LSTR  72           // LDS row stride in bf16 (144 B = 36 dwords === 4 mod 32)
#define QSCALE 0.18033688011112442f   // 0.125 * log2(e)
#define MASKED -1.0e6f

// workspace layout
#define WS_CNT_SZ  4096                         // 1024 x uint flags
#define WS_LM_OFF  4096
#define WS_LM_SZ   (2048 * 64 * 8)              // float2 (m,l) per query per item = 1 MB
#define WS_O_OFF   (WS_LM_OFF + WS_LM_SZ)       // 1052672
#define WS_O_SZ    (2048 * 4096 * 4)            // 32 MB of partial O
#define WS_NEEDED  ((size_t)WS_O_OFF + (size_t)WS_O_SZ)   // 34607104

typedef __attribute__((ext_vector_type(8))) short bf16x8;
typedef __attribute__((ext_vector_type(4))) float f32x4;

__device__ __forceinline__ uint pack2_trunc(float lo, float hi) {
    // [bf16(hi) : bf16(lo)] by byte-select (truncation) — one v_perm_b32
    return __builtin_amdgcn_perm(__float_as_uint(hi), __float_as_uint(lo), 0x07060302);
}
__device__ __forceinline__ ushort f2bf_rne(float x) {
    uint u = __float_as_uint(x);
    return (ushort)((u + 0x7fffu + ((u >> 16) & 1u)) >> 16);
}

// ---- combine: out[pair] = (O1*w1 + O2*w2) / (l1*w1 + l2*w2), exp2 domain ----
__device__ __forceinline__ void combine_pair(
    int pid, const int* __restrict__ valid_lens,
    const float2* __restrict__ lmbuf, const float* __restrict__ opart,
    float* __restrict__ out, int t)
{
    const int b  = pid & 63;
    const int qt = pid >> 6;
    const int vl = valid_lens[b];
    const bool has2 = !(vl != 0 && vl <= HALFT * BC);   // item2 empty iff 0 < vl <= 512
    const int i1 = pid * 2;
    const int qr = t >> 2;        // 64 query rows, 4 threads each
    const int c4 = t & 3;

    float2 ml1 = lmbuf[(size_t)i1 * 64 + qr];
    float w1, w2 = 0.f, denom;
    if (has2) {
        float2 ml2 = lmbuf[(size_t)(i1 + 1) * 64 + qr];
        float M = fmaxf(ml1.x, ml2.x);
        w1 = exp2f(ml1.x - M);
        w2 = exp2f(ml2.x - M);
        denom = ml1.y * w1 + ml2.y * w2;
    } else {
        w1 = 1.f;
        denom = ml1.y;
    }
    float inv = 1.f / denom;
    w1 *= inv; w2 *= inv;

    const float4* o1 = (const float4*)(opart + (size_t)i1 * (BQ * DIM));
    const float4* o2 = (const float4*)(opart + (size_t)(i1 + 1) * (BQ * DIM));
    float4* ob = (float4*)(out + ((size_t)b * SEQ + (size_t)qt * BQ) * DIM);
    #pragma unroll
    for (int j = 0; j < 4; j++) {
        int idx = qr * 16 + j * 4 + c4;   // lanes 0..3 cover 64 contiguous bytes
        float4 a = o1[idx];
        float4 r;
        r.x = a.x * w1; r.y = a.y * w1; r.z = a.z * w1; r.w = a.w * w1;
        if (has2) {
            float4 bb = o2[idx];
            r.x += bb.x * w2; r.y += bb.y * w2; r.z += bb.z * w2; r.w += bb.w * w2;
        }
        ob[idx] = r;
    }
}

__global__ __launch_bounds__(256, 4) void attn_mfma_splitk(
    const float* __restrict__ q, const float* __restrict__ k,
    const float* __restrict__ v, const int* __restrict__ valid_lens,
    float* __restrict__ out, uint* __restrict__ cnt,
    float2* __restrict__ lmbuf, float* __restrict__ opart)
{
    __shared__ ushort KPs[BC * LSTR];   // K tile; after barrier C, P tile (alias)
    __shared__ ushort Vt[DIM * LSTR];   // [d][key]
    __shared__ uint old_sh;

    const int t    = threadIdx.x;
    const int wave = t >> 6;
    const int wl   = t & 63;
    const int QD   = wl >> 4;          // quad 0..3
    const int li   = wl & 15;          // lane-in-quad 0..15
    // batch-major swizzle: all items of a batch land on the same XCD;
    // pair partner = bid + 64 -> also same XCD (64 % 8 == 0).
    const int b    = blockIdx.x & 63;
    const int rest = blockIdx.x >> 6;
    const int half = rest & 1;
    const int qt   = rest >> 1;
    const int q0   = qt * BQ;
    const int pid  = (qt << 6) | b;    // 0..1023
    const int item = pid * 2 + half;
    const int vl   = valid_lens[b];

    const size_t boff = (size_t)b * SEQ * DIM;

    const int it_full  = (vl == 0) ? NKT : ((vl + BC - 1) >> 6);
    const int it_begin = half * HALFT;
    const int it_end   = min(it_full, it_begin + HALFT);

    if (it_begin >= it_end) {
        // empty second half (0 < vl <= 512): partner holds everything
        if (t == 0) old_sh = atomicAdd(&cnt[pid], 1u);
        __syncthreads();
        if (old_sh == 1) {
            __threadfence();
            combine_pair(pid, valid_lens, lmbuf, opart, out, t);
        }
        return;
    }

    // ---- Q fragments straight into registers (B-operand), pre-scaled ----
    bf16x8 qb[2];
    {
        const float* qrow = q + boff + (size_t)(q0 + wave * 16 + li) * DIM + QD * 8;
        #pragma unroll
        for (int kc = 0; kc < 2; kc++) {
            float4 a = *(const float4*)(qrow + kc * 32);
            float4 c = *(const float4*)(qrow + kc * 32 + 4);
            union { bf16x8 v; ushort u[8]; } tmp;
            tmp.u[0] = f2bf_rne(a.x * QSCALE);
            tmp.u[1] = f2bf_rne(a.y * QSCALE);
            tmp.u[2] = f2bf_rne(a.z * QSCALE);
            tmp.u[3] = f2bf_rne(a.w * QSCALE);
            tmp.u[4] = f2bf_rne(c.x * QSCALE);
            tmp.u[5] = f2bf_rne(c.y * QSCALE);
            tmp.u[6] = f2bf_rne(c.z * QSCALE);
            tmp.u[7] = f2bf_rne(c.w * QSCALE);
            qb[kc] = tmp.v;
        }
    }

    // ---- prefetch registers ----
    float4 kf[4];          // K tile: 4 coalesced float4 per thread
    float  vf[2][8];       // V gather: (d = lane, 8 consecutive keys) x 2 slots

    auto load_tile = [&](int it) {
        const float4* kg = (const float4*)(k + boff + (size_t)it * BC * DIM);
        #pragma unroll
        for (int i = 0; i < 4; i++) kf[i] = kg[t + 256 * i];
        const float* vgf = v + boff + (size_t)it * BC * DIM;
        #pragma unroll
        for (int i = 0; i < 2; i++) {
            int slot = t + 256 * i;
            int d = slot & 63, ko = slot >> 6;
            #pragma unroll
            for (int j = 0; j < 8; j++)
                vf[i][j] = vgf[(size_t)(ko * 8 + j) * DIM + d];
        }
    };

    auto stage = [&]() {
        #pragma unroll
        for (int i = 0; i < 4; i++) {
            int idx = t + 256 * i;
            int row = idx >> 4, c4 = idx & 15;
            uint2 w;
            w.x = pack2_trunc(kf[i].x, kf[i].y);
            w.y = pack2_trunc(kf[i].z, kf[i].w);
            *(uint2*)&KPs[row * LSTR + c4 * 4] = w;
        }
        #pragma unroll
        for (int i = 0; i < 2; i++) {
            int slot = t + 256 * i;
            int d = slot & 63, ko = slot >> 6;
            uint4 w;
            w.x = pack2_trunc(vf[i][0], vf[i][1]);
            w.y = pack2_trunc(vf[i][2], vf[i][3]);
            w.z = pack2_trunc(vf[i][4], vf[i][5]);
            w.w = pack2_trunc(vf[i][6], vf[i][7]);
            *(uint4*)&Vt[d * LSTR + ko * 8] = w;   // b128, bank-uniform
        }
    };

    float m_run = -INFINITY, l_run = 0.f;
    f32x4 acc[4];
    #pragma unroll
    for (int dt = 0; dt < 4; dt++) acc[dt] = (f32x4){0.f, 0.f, 0.f, 0.f};

    load_tile(it_begin);

    for (int it = it_begin; it < it_end; it++) {
        __syncthreads();                  // (A) prior tile's P/V LDS reads done
        stage();
        if (it + 1 < it_end) load_tile(it + 1);   // in flight across compute
        __syncthreads();                  // (B) staging visible

        // ---- S^T = K x Q^T : rows = keys (QD*4+r), cols = queries (li) ----
        f32x4 sc[4];
        #pragma unroll
        for (int kt = 0; kt < 4; kt++) {
            bf16x8 ka0 = *(const bf16x8*)&KPs[(kt * 16 + li) * LSTR + QD * 8];
            bf16x8 ka1 = *(const bf16x8*)&KPs[(kt * 16 + li) * LSTR + 32 + QD * 8];
            f32x4 c = (f32x4){0.f, 0.f, 0.f, 0.f};
            c = __builtin_amdgcn_mfma_f32_16x16x32_bf16(ka0, qb[0], c, 0, 0, 0);
            c = __builtin_amdgcn_mfma_f32_16x16x32_bf16(ka1, qb[1], c, 0, 0, 0);
            sc[kt] = c;
        }

        __syncthreads();                  // (C) all waves done reading K -> region becomes P

        // ---- mask (only the boundary/invalid tiles pay per-element cost) ----
        const int kbase = it * BC;
        if (kbase + BC > vl) {
            #pragma unroll
            for (int kt = 0; kt < 4; kt++)
                #pragma unroll
                for (int r = 0; r < 4; r++) {
                    int key = kbase + kt * 16 + QD * 4 + r;
                    if (key >= vl) sc[kt][r] = MASKED;
                }
        }

        // ---- online softmax in exp2 domain (row = query = li) ----
        float mt = -INFINITY;
        #pragma unroll
        for (int kt = 0; kt < 4; kt++)
            #pragma unroll
            for (int r = 0; r < 4; r++) mt = fmaxf(mt, sc[kt][r]);
        mt = fmaxf(mt, __shfl_xor(mt, 16, 64));
        mt = fmaxf(mt, __shfl_xor(mt, 32, 64));
        float mn = fmaxf(m_run, mt);
        float alpha = exp2f(m_run - mn);   // -inf on first tile -> 0
        m_run = mn;

        float ls = 0.f;
        #pragma unroll
        for (int kt = 0; kt < 4; kt++) {
            float p0 = exp2f(sc[kt][0] - mn);
            float p1 = exp2f(sc[kt][1] - mn);
            float p2 = exp2f(sc[kt][2] - mn);
            float p3 = exp2f(sc[kt][3] - mn);
            ls += (p0 + p1) + (p2 + p3);
            uint2 w;
            w.x = pack2_trunc(p0, p1);
            w.y = pack2_trunc(p2, p3);
            *(uint2*)&KPs[(wave * 16 + li) * LSTR + kt * 16 + QD * 4] = w;
        }
        ls += __shfl_xor(ls, 16, 64);
        ls += __shfl_xor(ls, 32, 64);
        l_run = l_run * alpha + ls;

        // rescale O accumulator rows (row = QD*4+r holds query QD*4+r)
        float a0 = __shfl(alpha, QD * 4 + 0, 64);
        float a1 = __shfl(alpha, QD * 4 + 1, 64);
        float a2 = __shfl(alpha, QD * 4 + 2, 64);
        float a3 = __shfl(alpha, QD * 4 + 3, 64);
        #pragma unroll
        for (int dt = 0; dt < 4; dt++) {
            acc[dt][0] *= a0; acc[dt][1] *= a1;
            acc[dt][2] *= a2; acc[dt][3] *= a3;
        }

        // ---- PV: O += P x V (same-wave LDS round-trip for P; P rows wave-private) ----
        bf16x8 pa0 = *(const bf16x8*)&KPs[(wave * 16 + li) * LSTR + QD * 8];
        bf16x8 pa1 = *(const bf16x8*)&KPs[(wave * 16 + li) * LSTR + 32 + QD * 8];
        #pragma unroll
        for (int dt = 0; dt < 4; dt++) {
            bf16x8 vb0 = *(const bf16x8*)&Vt[(dt * 16 + li) * LSTR + QD * 8];
            bf16x8 vb1 = *(const bf16x8*)&Vt[(dt * 16 + li) * LSTR + 32 + QD * 8];
            acc[dt] = __builtin_amdgcn_mfma_f32_16x16x32_bf16(pa0, vb0, acc[dt], 0, 0, 0);
            acc[dt] = __builtin_amdgcn_mfma_f32_16x16x32_bf16(pa1, vb1, acc[dt], 0, 0, 0);
        }
    }

    // ---- epilogue: write UNNORMALIZED partial + (m,l), then flag ----
    if (QD == 0)
        lmbuf[(size_t)item * 64 + wave * 16 + li] = make_float2(m_run, l_run);

    {
        float* ob = opart + (size_t)item * (BQ * DIM);
        const int rbase = wave * 16 + QD * 4;
        #pragma unroll
        for (int dt = 0; dt < 4; dt++) {
            int col = dt * 16 + li;
            ob[(size_t)(rbase + 0) * DIM + col] = acc[dt][0];
            ob[(size_t)(rbase + 1) * DIM + col] = acc[dt][1];
            ob[(size_t)(rbase + 2) * DIM + col] = acc[dt][2];
            ob[(size_t)(rbase + 3) * DIM + col] = acc[dt][3];
        }
    }

    __threadfence();                       // release partials (device scope)
    if (t == 0) old_sh = atomicAdd(&cnt[pid], 1u);
    __syncthreads();
    if (old_sh == 1) {                     // last finisher combines
        __threadfence();                   // acquire partner's partials
        combine_pair(pid, valid_lens, lmbuf, opart, out, t);
    }
}

// ---------------- fallback (no/short workspace): previous verified kernel ----------------
__global__ __launch_bounds__(256, 4) void attn_mfma_flash2(
    const float* __restrict__ q, const float* __restrict__ k,
    const float* __restrict__ v, const int* __restrict__ valid_lens,
    float* __restrict__ out)
{
    __shared__ ushort Ks[BC * LSTR];   // [key][d]
    __shared__ ushort Vt[DIM * LSTR];  // [d][key]
    __shared__ ushort Ps[BQ * LSTR];   // [query][key], wave-private 16-row bands

    const int t    = threadIdx.x;
    const int wave = t >> 6;
    const int wl   = t & 63;
    const int QD   = wl >> 4;
    const int li   = wl & 15;
    const int b    = blockIdx.x & 63;
    const int q0   = (blockIdx.x >> 6) * BQ;
    const int vl   = valid_lens[b];

    const size_t boff = (size_t)b * SEQ * DIM;

    bf16x8 qb[2];
    {
        const float* qrow = q + boff + (size_t)(q0 + wave * 16 + li) * DIM + QD * 8;
        #pragma unroll
        for (int kc = 0; kc < 2; kc++) {
            float4 a = *(const float4*)(qrow + kc * 32);
            float4 c = *(const float4*)(qrow + kc * 32 + 4);
            union { bf16x8 v; ushort u[8]; } tmp;
            tmp.u[0] = f2bf_rne(a.x * QSCALE);
            tmp.u[1] = f2bf_rne(a.y * QSCALE);
            tmp.u[2] = f2bf_rne(a.z * QSCALE);
            tmp.u[3] = f2bf_rne(a.w * QSCALE);
            tmp.u[4] = f2bf_rne(c.x * QSCALE);
            tmp.u[5] = f2bf_rne(c.y * QSCALE);
            tmp.u[6] = f2bf_rne(c.z * QSCALE);
            tmp.u[7] = f2bf_rne(c.w * QSCALE);
            qb[kc] = tmp.v;
        }
    }

    const int it_max = (vl == 0) ? NKT : ((vl + BC - 1) >> 6);

    float4 kf[4];
    float  vf[2][8];

    auto load_tile = [&](int it) {
        const float4* kg = (const float4*)(k + boff + (size_t)it * BC * DIM);
        #pragma unroll
        for (int i = 0; i < 4; i++) kf[i] = kg[t + 256 * i];
        const float* vgf = v + boff + (size_t)it * BC * DIM;
        #pragma unroll
        for (int i = 0; i < 2; i++) {
            int slot = t + 256 * i;
            int d = slot & 63, ko = slot >> 6;
            #pragma unroll
            for (int j = 0; j < 8; j++)
                vf[i][j] = vgf[(size_t)(ko * 8 + j) * DIM + d];
        }
    };

    auto stage = [&]() {
        #pragma unroll
        for (int i = 0; i < 4; i++) {
            int idx = t + 256 * i;
            int row = idx >> 4, c4 = idx & 15;
            uint2 w;
            w.x = pack2_trunc(kf[i].x, kf[i].y);
            w.y = pack2_trunc(kf[i].z, kf[i].w);
            *(uint2*)&Ks[row * LSTR + c4 * 4] = w;
        }
        #pragma unroll
        for (int i = 0; i < 2; i++) {
            int slot = t + 256 * i;
            int d = slot & 63, ko = slot >> 6;
            uint4 w;
            w.x = pack2_trunc(vf[i][0], vf[i][1]);
            w.y = pack2_trunc(vf[i][2], vf[i][3]);
            w.z = pack2_trunc(vf[i][4], vf[i][5]);
            w.w = pack2_trunc(vf[i][6], vf[i][7]);
            *(uint4*)&Vt[d * LSTR + ko * 8] = w;
        }
    };

    float m_run = -INFINITY, l_run = 0.f;
    f32x4 acc[4];
    #pragma unroll
    for (int dt = 0; dt < 4; dt++) acc[dt] = (f32x4){0.f, 0.f, 0.f, 0.f};

    load_tile(0);

    for (int it = 0; it < it_max; it++) {
        __syncthreads();
        stage();
        if (it + 1 < it_max) load_tile(it + 1);
        __syncthreads();

        f32x4 sc[4];
        #pragma unroll
        for (int kt = 0; kt < 4; kt++) {
            bf16x8 ka0 = *(const bf16x8*)&Ks[(kt * 16 + li) * LSTR + QD * 8];
            bf16x8 ka1 = *(const bf16x8*)&Ks[(kt * 16 + li) * LSTR + 32 + QD * 8];
            f32x4 c = (f32x4){0.f, 0.f, 0.f, 0.f};
            c = __builtin_amdgcn_mfma_f32_16x16x32_bf16(ka0, qb[0], c, 0, 0, 0);
            c = __builtin_amdgcn_mfma_f32_16x16x32_bf16(ka1, qb[1], c, 0, 0, 0);
            sc[kt] = c;
        }

        const int kbase = it * BC;
        if (kbase + BC > vl) {
            #pragma unroll
            for (int kt = 0; kt < 4; kt++)
                #pragma unroll
                for (int r = 0; r < 4; r++) {
                    int key = kbase + kt * 16 + QD * 4 + r;
                    if (key >= vl) sc[kt][r] = MASKED;
                }
        }

        float mt = -INFINITY;
        #pragma unroll
        for (int kt = 0; kt < 4; kt++)
            #pragma unroll
            for (int r = 0; r < 4; r++) mt = fmaxf(mt, sc[kt][r]);
        mt = fmaxf(mt, __shfl_xor(mt, 16, 64));
        mt = fmaxf(mt, __shfl_xor(mt, 32, 64));
        float mn = fmaxf(m_run, mt);
        float alpha = exp2f(m_run - mn);
        m_run = mn;

        float ls = 0.f;
        #pragma unroll
        for (int kt = 0; kt < 4; kt++) {
            float p0 = exp2f(sc[kt][0] - mn);
            float p1 = exp2f(sc[kt][1] - mn);
            float p2 = exp2f(sc[kt][2] - mn);
            float p3 = exp2f(sc[kt][3] - mn);
            ls += (p0 + p1) + (p2 + p3);
            uint2 w;
            w.x = pack2_trunc(p0, p1);
            w.y = pack2_trunc(p2, p3);
            *(uint2*)&Ps[(wave * 16 + li) * LSTR + kt * 16 + QD * 4] = w;
        }
        ls += __shfl_xor(ls, 16, 64);
        ls += __shfl_xor(ls, 32, 64);
        l_run = l_run * alpha + ls;

        float a0 = __shfl(alpha, QD * 4 + 0, 64);
        float a1 = __shfl(alpha, QD * 4 + 1, 64);
        float a2 = __shfl(alpha, QD * 4 + 2, 64);
        float a3 = __shfl(alpha, QD * 4 + 3, 64);
        #pragma unroll
        for (int dt = 0; dt < 4; dt++) {
            acc[dt][0] *= a0; acc[dt][1] *= a1;
            acc[dt][2] *= a2; acc[dt][3] *= a3;
        }

        bf16x8 pa0 = *(const bf16x8*)&Ps[(wave * 16 + li) * LSTR + QD * 8];
        bf16x8 pa1 = *(const bf16x8*)&Ps[(wave * 16 + li) * LSTR + 32 + QD * 8];
        #pragma unroll
        for (int dt = 0; dt < 4; dt++) {
            bf16x8 vb0 = *(const bf16x8*)&Vt[(dt * 16 + li) * LSTR + QD * 8];
            bf16x8 vb1 = *(const bf16x8*)&Vt[(dt * 16 + li) * LSTR + 32 + QD * 8];
            acc[dt] = __builtin_amdgcn_mfma_f32_16x16x32_bf16(pa0, vb0, acc[dt], 0, 0, 0);
            acc[dt] = __builtin_amdgcn_mfma_f32_16x16x32_bf16(pa1, vb1, acc[dt], 0, 0, 0);
        }
    }

    float invl = 1.0f / l_run;
    float i0 = __shfl(invl, QD * 4 + 0, 64);
    float i1 = __shfl(invl, QD * 4 + 1, 64);
    float i2 = __shfl(invl, QD * 4 + 2, 64);
    float i3 = __shfl(invl, QD * 4 + 3, 64);
    float* ob = out + boff + (size_t)q0 * DIM;
    const int rbase = wave * 16 + QD * 4;
    #pragma unroll
    for (int dt = 0; dt < 4; dt++) {
        int col = dt * 16 + li;
        ob[(size_t)(rbase + 0) * DIM + col] = acc[dt][0] * i0;
        ob[(size_t)(rbase + 1) * DIM + col] = acc[dt][1] * i1;
        ob[(size_t)(rbase + 2) * DIM + col] = acc[dt][2] * i2;
        ob[(size_t)(rbase + 3) * DIM + col] = acc[dt][3] * i3;
    }
}

extern "C" void kernel_launch(void* const* d_in, const int* in_sizes, int n_in,
                              void* d_out, int out_size, void* d_ws, size_t ws_size,
                              hipStream_t stream) {
    const float* q = (const float*)d_in[0];
    const float* k = (const float*)d_in[1];
    const float* v = (const float*)d_in[2];
    const int* valid_lens = (const int*)d_in[3];
    float* out = (float*)d_out;

    if (d_ws != nullptr && ws_size >= WS_NEEDED) {
        // split-K path: zero the 1024 pair flags, then one kernel (combine inside)
        hipMemsetAsync(d_ws, 0, WS_CNT_SZ, stream);
        uint*   cnt   = (uint*)d_ws;
        float2* lmbuf = (float2*)((char*)d_ws + WS_LM_OFF);
        float*  opart = (float*)((char*)d_ws + WS_O_OFF);
        dim3 grid(BATCH * (SEQ / BQ) * 2);   // 2048 blocks
        attn_mfma_splitk<<<grid, dim3(256), 0, stream>>>(
            q, k, v, valid_lens, out, cnt, lmbuf, opart);
    } else {
        dim3 grid(BATCH * (SEQ / BQ));       // 1024 blocks
        attn_mfma_flash2<<<grid, dim3(256), 0, stream>>>(q, k, v, valid_lens, out);
    }
}

// Round 3
// 134.259 us; speedup vs baseline: 5.0508x; 3.5707x over previous
//
#include <hip/hip_runtime.h>
#include <math.h>

// DotProductAttention B=64,S=1024,D=64 fp32, bf16-MFMA flash attention.
// Round 5: remove device-scope fence poison. Round-4's single-kernel split-K
// was correct but spent ~400us stalled: __threadfence() on gfx950 emits
// buffer_wbl2/buffer_inv (whole-L2 writeback+invalidate, L2s are per-XCD
// non-coherent) -> 16K serialized TCC cache ops + K/V working-set blown away.
// Fix: two dispatches on the same stream (kernel boundary = release/acquire),
// zero fences/atomics.
//   kernel1 (2048 blocks): split-K halves; vl<=512 pairs take a DIRECT-WRITE
//     fast path (half1 owns the whole range -> normalize + write out, no
//     partials); vl>512 (and vl==0) pairs write unnormalized partials + (m,l).
//   kernel2 (1024 blocks): combines only it_full>8 pairs; same-XCD as writer.
// LDS 18.4 KB -> 8 blocks/CU; VGPR 64 -> 8 waves/SIMD.
// Fallback to the single-kernel version if workspace too small.

#define BATCH 64
#define SEQ   1024
#define DIM   64
#define BQ    64           // queries per block (4 waves x 16)
#define BC    64           // keys per iteration
#define NKT   (SEQ / BC)   // 16
#define HALFT 8            // K-tiles per split-K item
#define LSTR  72           // LDS row stride in bf16 (144 B = 36 dwords === 4 mod 32)
#define QSCALE 0.18033688011112442f   // 0.125 * log2(e)
#define MASKED -1.0e6f

// workspace layout (no flags needed anymore)
#define WS_LM_SZ   (2048 * 64 * 8)              // float2 (m,l) per query per item = 1 MB
#define WS_O_OFF   WS_LM_SZ                     // 1048576
#define WS_O_SZ    (2048 * 4096 * 4)            // 32 MB of partial O
#define WS_NEEDED  ((size_t)WS_O_OFF + (size_t)WS_O_SZ)

typedef __attribute__((ext_vector_type(8))) short bf16x8;
typedef __attribute__((ext_vector_type(4))) float f32x4;

__device__ __forceinline__ uint pack2_trunc(float lo, float hi) {
    // [bf16(hi) : bf16(lo)] by byte-select (truncation) — one v_perm_b32
    return __builtin_amdgcn_perm(__float_as_uint(hi), __float_as_uint(lo), 0x07060302);
}
__device__ __forceinline__ ushort f2bf_rne(float x) {
    uint u = __float_as_uint(x);
    return (ushort)((u + 0x7fffu + ((u >> 16) & 1u)) >> 16);
}

__global__ __launch_bounds__(256, 4) void attn_mfma_splitk(
    const float* __restrict__ q, const float* __restrict__ k,
    const float* __restrict__ v, const int* __restrict__ valid_lens,
    float* __restrict__ out,
    float2* __restrict__ lmbuf, float* __restrict__ opart)
{
    __shared__ ushort KPs[BC * LSTR];   // K tile; after barrier C, P tile (alias)
    __shared__ ushort Vt[DIM * LSTR];   // [d][key]

    const int t    = threadIdx.x;
    const int wave = t >> 6;
    const int wl   = t & 63;
    const int QD   = wl >> 4;          // quad 0..3
    const int li   = wl & 15;          // lane-in-quad 0..15
    // batch-major swizzle: all items of a batch land on the same XCD;
    // pair partner = bid + 64 -> also same XCD (64 % 8 == 0).
    const int b    = blockIdx.x & 63;
    const int rest = blockIdx.x >> 6;
    const int half = rest & 1;
    const int qt   = rest >> 1;
    const int q0   = qt * BQ;
    const int pid  = (qt << 6) | b;    // 0..1023
    const int item = pid * 2 + half;
    const int vl   = valid_lens[b];

    const size_t boff = (size_t)b * SEQ * DIM;

    const int it_full  = (vl == 0) ? NKT : ((vl + BC - 1) >> 6);
    const int it_begin = half * HALFT;
    const int it_end   = min(it_full, it_begin + HALFT);

    if (it_begin >= it_end) return;    // empty second half: partner direct-writes

    const bool direct = (half == 0) && (it_full <= HALFT);  // own the whole range

    // ---- Q fragments straight into registers (B-operand), pre-scaled ----
    bf16x8 qb[2];
    {
        const float* qrow = q + boff + (size_t)(q0 + wave * 16 + li) * DIM + QD * 8;
        #pragma unroll
        for (int kc = 0; kc < 2; kc++) {
            float4 a = *(const float4*)(qrow + kc * 32);
            float4 c = *(const float4*)(qrow + kc * 32 + 4);
            union { bf16x8 v; ushort u[8]; } tmp;
            tmp.u[0] = f2bf_rne(a.x * QSCALE);
            tmp.u[1] = f2bf_rne(a.y * QSCALE);
            tmp.u[2] = f2bf_rne(a.z * QSCALE);
            tmp.u[3] = f2bf_rne(a.w * QSCALE);
            tmp.u[4] = f2bf_rne(c.x * QSCALE);
            tmp.u[5] = f2bf_rne(c.y * QSCALE);
            tmp.u[6] = f2bf_rne(c.z * QSCALE);
            tmp.u[7] = f2bf_rne(c.w * QSCALE);
            qb[kc] = tmp.v;
        }
    }

    // ---- prefetch registers ----
    float4 kf[4];          // K tile: 4 coalesced float4 per thread
    float  vf[2][8];       // V gather: (d = lane, 8 consecutive keys) x 2 slots

    auto load_tile = [&](int it) {
        const float4* kg = (const float4*)(k + boff + (size_t)it * BC * DIM);
        #pragma unroll
        for (int i = 0; i < 4; i++) kf[i] = kg[t + 256 * i];
        const float* vgf = v + boff + (size_t)it * BC * DIM;
        #pragma unroll
        for (int i = 0; i < 2; i++) {
            int slot = t + 256 * i;
            int d = slot & 63, ko = slot >> 6;
            #pragma unroll
            for (int j = 0; j < 8; j++)
                vf[i][j] = vgf[(size_t)(ko * 8 + j) * DIM + d];
        }
    };

    auto stage = [&]() {
        #pragma unroll
        for (int i = 0; i < 4; i++) {
            int idx = t + 256 * i;
            int row = idx >> 4, c4 = idx & 15;
            uint2 w;
            w.x = pack2_trunc(kf[i].x, kf[i].y);
            w.y = pack2_trunc(kf[i].z, kf[i].w);
            *(uint2*)&KPs[row * LSTR + c4 * 4] = w;
        }
        #pragma unroll
        for (int i = 0; i < 2; i++) {
            int slot = t + 256 * i;
            int d = slot & 63, ko = slot >> 6;
            uint4 w;
            w.x = pack2_trunc(vf[i][0], vf[i][1]);
            w.y = pack2_trunc(vf[i][2], vf[i][3]);
            w.z = pack2_trunc(vf[i][4], vf[i][5]);
            w.w = pack2_trunc(vf[i][6], vf[i][7]);
            *(uint4*)&Vt[d * LSTR + ko * 8] = w;   // b128, bank-uniform
        }
    };

    float m_run = -INFINITY, l_run = 0.f;
    f32x4 acc[4];
    #pragma unroll
    for (int dt = 0; dt < 4; dt++) acc[dt] = (f32x4){0.f, 0.f, 0.f, 0.f};

    load_tile(it_begin);

    for (int it = it_begin; it < it_end; it++) {
        __syncthreads();                  // (A) prior tile's P/V LDS reads done
        stage();
        if (it + 1 < it_end) load_tile(it + 1);   // in flight across compute
        __syncthreads();                  // (B) staging visible

        // ---- S^T = K x Q^T : rows = keys (QD*4+r), cols = queries (li) ----
        f32x4 sc[4];
        #pragma unroll
        for (int kt = 0; kt < 4; kt++) {
            bf16x8 ka0 = *(const bf16x8*)&KPs[(kt * 16 + li) * LSTR + QD * 8];
            bf16x8 ka1 = *(const bf16x8*)&KPs[(kt * 16 + li) * LSTR + 32 + QD * 8];
            f32x4 c = (f32x4){0.f, 0.f, 0.f, 0.f};
            c = __builtin_amdgcn_mfma_f32_16x16x32_bf16(ka0, qb[0], c, 0, 0, 0);
            c = __builtin_amdgcn_mfma_f32_16x16x32_bf16(ka1, qb[1], c, 0, 0, 0);
            sc[kt] = c;
        }

        __syncthreads();                  // (C) all waves done reading K -> region becomes P

        // ---- mask (only the boundary/invalid tiles pay per-element cost) ----
        const int kbase = it * BC;
        if (kbase + BC > vl) {
            #pragma unroll
            for (int kt = 0; kt < 4; kt++)
                #pragma unroll
                for (int r = 0; r < 4; r++) {
                    int key = kbase + kt * 16 + QD * 4 + r;
                    if (key >= vl) sc[kt][r] = MASKED;
                }
        }

        // ---- online softmax in exp2 domain (row = query = li) ----
        float mt = -INFINITY;
        #pragma unroll
        for (int kt = 0; kt < 4; kt++)
            #pragma unroll
            for (int r = 0; r < 4; r++) mt = fmaxf(mt, sc[kt][r]);
        mt = fmaxf(mt, __shfl_xor(mt, 16, 64));
        mt = fmaxf(mt, __shfl_xor(mt, 32, 64));
        float mn = fmaxf(m_run, mt);
        float alpha = exp2f(m_run - mn);   // -inf on first tile -> 0
        m_run = mn;

        float ls = 0.f;
        #pragma unroll
        for (int kt = 0; kt < 4; kt++) {
            float p0 = exp2f(sc[kt][0] - mn);
            float p1 = exp2f(sc[kt][1] - mn);
            float p2 = exp2f(sc[kt][2] - mn);
            float p3 = exp2f(sc[kt][3] - mn);
            ls += (p0 + p1) + (p2 + p3);
            uint2 w;
            w.x = pack2_trunc(p0, p1);
            w.y = pack2_trunc(p2, p3);
            *(uint2*)&KPs[(wave * 16 + li) * LSTR + kt * 16 + QD * 4] = w;
        }
        ls += __shfl_xor(ls, 16, 64);
        ls += __shfl_xor(ls, 32, 64);
        l_run = l_run * alpha + ls;

        // rescale O accumulator rows (row = QD*4+r holds query QD*4+r)
        float a0 = __shfl(alpha, QD * 4 + 0, 64);
        float a1 = __shfl(alpha, QD * 4 + 1, 64);
        float a2 = __shfl(alpha, QD * 4 + 2, 64);
        float a3 = __shfl(alpha, QD * 4 + 3, 64);
        #pragma unroll
        for (int dt = 0; dt < 4; dt++) {
            acc[dt][0] *= a0; acc[dt][1] *= a1;
            acc[dt][2] *= a2; acc[dt][3] *= a3;
        }

        // ---- PV: O += P x V (same-wave LDS round-trip for P; P rows wave-private) ----
        bf16x8 pa0 = *(const bf16x8*)&KPs[(wave * 16 + li) * LSTR + QD * 8];
        bf16x8 pa1 = *(const bf16x8*)&KPs[(wave * 16 + li) * LSTR + 32 + QD * 8];
        #pragma unroll
        for (int dt = 0; dt < 4; dt++) {
            bf16x8 vb0 = *(const bf16x8*)&Vt[(dt * 16 + li) * LSTR + QD * 8];
            bf16x8 vb1 = *(const bf16x8*)&Vt[(dt * 16 + li) * LSTR + 32 + QD * 8];
            acc[dt] = __builtin_amdgcn_mfma_f32_16x16x32_bf16(pa0, vb0, acc[dt], 0, 0, 0);
            acc[dt] = __builtin_amdgcn_mfma_f32_16x16x32_bf16(pa1, vb1, acc[dt], 0, 0, 0);
        }
    }

    if (direct) {
        // ---- fast path: this item owns the whole softmax range ----
        float invl = 1.0f / l_run;
        float i0 = __shfl(invl, QD * 4 + 0, 64);
        float i1 = __shfl(invl, QD * 4 + 1, 64);
        float i2 = __shfl(invl, QD * 4 + 2, 64);
        float i3 = __shfl(invl, QD * 4 + 3, 64);
        float* ob = out + boff + (size_t)q0 * DIM;
        const int rbase = wave * 16 + QD * 4;
        #pragma unroll
        for (int dt = 0; dt < 4; dt++) {
            int col = dt * 16 + li;
            ob[(size_t)(rbase + 0) * DIM + col] = acc[dt][0] * i0;
            ob[(size_t)(rbase + 1) * DIM + col] = acc[dt][1] * i1;
            ob[(size_t)(rbase + 2) * DIM + col] = acc[dt][2] * i2;
            ob[(size_t)(rbase + 3) * DIM + col] = acc[dt][3] * i3;
        }
    } else {
        // ---- write UNNORMALIZED partial + (m,l); kernel2 combines ----
        if (QD == 0)
            lmbuf[(size_t)item * 64 + wave * 16 + li] = make_float2(m_run, l_run);
        float* ob = opart + (size_t)item * (BQ * DIM);
        const int rbase = wave * 16 + QD * 4;
        #pragma unroll
        for (int dt = 0; dt < 4; dt++) {
            int col = dt * 16 + li;
            ob[(size_t)(rbase + 0) * DIM + col] = acc[dt][0];
            ob[(size_t)(rbase + 1) * DIM + col] = acc[dt][1];
            ob[(size_t)(rbase + 2) * DIM + col] = acc[dt][2];
            ob[(size_t)(rbase + 3) * DIM + col] = acc[dt][3];
        }
    }
}

// ---- kernel 2: combine the two halves of pairs with it_full > HALFT ----
__global__ __launch_bounds__(256) void attn_combine(
    const int* __restrict__ valid_lens,
    const float2* __restrict__ lmbuf, const float* __restrict__ opart,
    float* __restrict__ out)
{
    const int pid = blockIdx.x;        // 0..1023, XCD pid%8 == writer's XCD
    const int b   = pid & 63;
    const int qt  = pid >> 6;
    const int vl  = valid_lens[b];
    const int it_full = (vl == 0) ? NKT : ((vl + BC - 1) >> 6);
    if (it_full <= HALFT) return;      // direct path already wrote out

    const int t  = threadIdx.x;
    const int qr = t >> 2;             // 64 query rows, 4 threads each
    const int c4 = t & 3;
    const int i1 = pid * 2;

    float2 ml1 = lmbuf[(size_t)i1 * 64 + qr];
    float2 ml2 = lmbuf[(size_t)(i1 + 1) * 64 + qr];
    float M  = fmaxf(ml1.x, ml2.x);
    float w1 = exp2f(ml1.x - M);
    float w2 = exp2f(ml2.x - M);
    float inv = 1.f / (ml1.y * w1 + ml2.y * w2);
    w1 *= inv; w2 *= inv;

    const float4* o1 = (const float4*)(opart + (size_t)i1 * (BQ * DIM));
    const float4* o2 = (const float4*)(opart + (size_t)(i1 + 1) * (BQ * DIM));
    float4* ob = (float4*)(out + ((size_t)b * SEQ + (size_t)qt * BQ) * DIM);
    #pragma unroll
    for (int j = 0; j < 4; j++) {
        int idx = qr * 16 + j * 4 + c4;   // lanes 0..3 cover 64 contiguous bytes
        float4 a  = o1[idx];
        float4 bb = o2[idx];
        float4 r;
        r.x = a.x * w1 + bb.x * w2;
        r.y = a.y * w1 + bb.y * w2;
        r.z = a.z * w1 + bb.z * w2;
        r.w = a.w * w1 + bb.w * w2;
        ob[idx] = r;
    }
}

// ---------------- fallback (no/short workspace): round-0 verified kernel ----------------
__global__ __launch_bounds__(256, 4) void attn_mfma_flash2(
    const float* __restrict__ q, const float* __restrict__ k,
    const float* __restrict__ v, const int* __restrict__ valid_lens,
    float* __restrict__ out)
{
    __shared__ ushort Ks[BC * LSTR];   // [key][d]
    __shared__ ushort Vt[DIM * LSTR];  // [d][key]
    __shared__ ushort Ps[BQ * LSTR];   // [query][key], wave-private 16-row bands

    const int t    = threadIdx.x;
    const int wave = t >> 6;
    const int wl   = t & 63;
    const int QD   = wl >> 4;
    const int li   = wl & 15;
    const int b    = blockIdx.x & 63;
    const int q0   = (blockIdx.x >> 6) * BQ;
    const int vl   = valid_lens[b];

    const size_t boff = (size_t)b * SEQ * DIM;

    bf16x8 qb[2];
    {
        const float* qrow = q + boff + (size_t)(q0 + wave * 16 + li) * DIM + QD * 8;
        #pragma unroll
        for (int kc = 0; kc < 2; kc++) {
            float4 a = *(const float4*)(qrow + kc * 32);
            float4 c = *(const float4*)(qrow + kc * 32 + 4);
            union { bf16x8 v; ushort u[8]; } tmp;
            tmp.u[0] = f2bf_rne(a.x * QSCALE);
            tmp.u[1] = f2bf_rne(a.y * QSCALE);
            tmp.u[2] = f2bf_rne(a.z * QSCALE);
            tmp.u[3] = f2bf_rne(a.w * QSCALE);
            tmp.u[4] = f2bf_rne(c.x * QSCALE);
            tmp.u[5] = f2bf_rne(c.y * QSCALE);
            tmp.u[6] = f2bf_rne(c.z * QSCALE);
            tmp.u[7] = f2bf_rne(c.w * QSCALE);
            qb[kc] = tmp.v;
        }
    }

    const int it_max = (vl == 0) ? NKT : ((vl + BC - 1) >> 6);

    float4 kf[4];
    float  vf[2][8];

    auto load_tile = [&](int it) {
        const float4* kg = (const float4*)(k + boff + (size_t)it * BC * DIM);
        #pragma unroll
        for (int i = 0; i < 4; i++) kf[i] = kg[t + 256 * i];
        const float* vgf = v + boff + (size_t)it * BC * DIM;
        #pragma unroll
        for (int i = 0; i < 2; i++) {
            int slot = t + 256 * i;
            int d = slot & 63, ko = slot >> 6;
            #pragma unroll
            for (int j = 0; j < 8; j++)
                vf[i][j] = vgf[(size_t)(ko * 8 + j) * DIM + d];
        }
    };

    auto stage = [&]() {
        #pragma unroll
        for (int i = 0; i < 4; i++) {
            int idx = t + 256 * i;
            int row = idx >> 4, c4 = idx & 15;
            uint2 w;
            w.x = pack2_trunc(kf[i].x, kf[i].y);
            w.y = pack2_trunc(kf[i].z, kf[i].w);
            *(uint2*)&Ks[row * LSTR + c4 * 4] = w;
        }
        #pragma unroll
        for (int i = 0; i < 2; i++) {
            int slot = t + 256 * i;
            int d = slot & 63, ko = slot >> 6;
            uint4 w;
            w.x = pack2_trunc(vf[i][0], vf[i][1]);
            w.y = pack2_trunc(vf[i][2], vf[i][3]);
            w.z = pack2_trunc(vf[i][4], vf[i][5]);
            w.w = pack2_trunc(vf[i][6], vf[i][7]);
            *(uint4*)&Vt[d * LSTR + ko * 8] = w;
        }
    };

    float m_run = -INFINITY, l_run = 0.f;
    f32x4 acc[4];
    #pragma unroll
    for (int dt = 0; dt < 4; dt++) acc[dt] = (f32x4){0.f, 0.f, 0.f, 0.f};

    load_tile(0);

    for (int it = 0; it < it_max; it++) {
        __syncthreads();
        stage();
        if (it + 1 < it_max) load_tile(it + 1);
        __syncthreads();

        f32x4 sc[4];
        #pragma unroll
        for (int kt = 0; kt < 4; kt++) {
            bf16x8 ka0 = *(const bf16x8*)&Ks[(kt * 16 + li) * LSTR + QD * 8];
            bf16x8 ka1 = *(const bf16x8*)&Ks[(kt * 16 + li) * LSTR + 32 + QD * 8];
            f32x4 c = (f32x4){0.f, 0.f, 0.f, 0.f};
            c = __builtin_amdgcn_mfma_f32_16x16x32_bf16(ka0, qb[0], c, 0, 0, 0);
            c = __builtin_amdgcn_mfma_f32_16x16x32_bf16(ka1, qb[1], c, 0, 0, 0);
            sc[kt] = c;
        }

        const int kbase = it * BC;
        if (kbase + BC > vl) {
            #pragma unroll
            for (int kt = 0; kt < 4; kt++)
                #pragma unroll
                for (int r = 0; r < 4; r++) {
                    int key = kbase + kt * 16 + QD * 4 + r;
                    if (key >= vl) sc[kt][r] = MASKED;
                }
        }

        float mt = -INFINITY;
        #pragma unroll
        for (int kt = 0; kt < 4; kt++)
            #pragma unroll
            for (int r = 0; r < 4; r++) mt = fmaxf(mt, sc[kt][r]);
        mt = fmaxf(mt, __shfl_xor(mt, 16, 64));
        mt = fmaxf(mt, __shfl_xor(mt, 32, 64));
        float mn = fmaxf(m_run, mt);
        float alpha = exp2f(m_run - mn);
        m_run = mn;

        float ls = 0.f;
        #pragma unroll
        for (int kt = 0; kt < 4; kt++) {
            float p0 = exp2f(sc[kt][0] - mn);
            float p1 = exp2f(sc[kt][1] - mn);
            float p2 = exp2f(sc[kt][2] - mn);
            float p3 = exp2f(sc[kt][3] - mn);
            ls += (p0 + p1) + (p2 + p3);
            uint2 w;
            w.x = pack2_trunc(p0, p1);
            w.y = pack2_trunc(p2, p3);
            *(uint2*)&Ps[(wave * 16 + li) * LSTR + kt * 16 + QD * 4] = w;
        }
        ls += __shfl_xor(ls, 16, 64);
        ls += __shfl_xor(ls, 32, 64);
        l_run = l_run * alpha + ls;

        float a0 = __shfl(alpha, QD * 4 + 0, 64);
        float a1 = __shfl(alpha, QD * 4 + 1, 64);
        float a2 = __shfl(alpha, QD * 4 + 2, 64);
        float a3 = __shfl(alpha, QD * 4 + 3, 64);
        #pragma unroll
        for (int dt = 0; dt < 4; dt++) {
            acc[dt][0] *= a0; acc[dt][1] *= a1;
            acc[dt][2] *= a2; acc[dt][3] *= a3;
        }

        bf16x8 pa0 = *(const bf16x8*)&Ps[(wave * 16 + li) * LSTR + QD * 8];
        bf16x8 pa1 = *(const bf16x8*)&Ps[(wave * 16 + li) * LSTR + 32 + QD * 8];
        #pragma unroll
        for (int dt = 0; dt < 4; dt++) {
            bf16x8 vb0 = *(const bf16x8*)&Vt[(dt * 16 + li) * LSTR + QD * 8];
            bf16x8 vb1 = *(const bf16x8*)&Vt[(dt * 16 + li) * LSTR + 32 + QD * 8];
            acc[dt] = __builtin_amdgcn_mfma_f32_16x16x32_bf16(pa0, vb0, acc[dt], 0, 0, 0);
            acc[dt] = __builtin_amdgcn_mfma_f32_16x16x32_bf16(pa1, vb1, acc[dt], 0, 0, 0);
        }
    }

    float invl = 1.0f / l_run;
    float i0 = __shfl(invl, QD * 4 + 0, 64);
    float i1 = __shfl(invl, QD * 4 + 1, 64);
    float i2 = __shfl(invl, QD * 4 + 2, 64);
    float i3 = __shfl(invl, QD * 4 + 3, 64);
    float* ob = out + boff + (size_t)q0 * DIM;
    const int rbase = wave * 16 + QD * 4;
    #pragma unroll
    for (int dt = 0; dt < 4; dt++) {
        int col = dt * 16 + li;
        ob[(size_t)(rbase + 0) * DIM + col] = acc[dt][0] * i0;
        ob[(size_t)(rbase + 1) * DIM + col] = acc[dt][1] * i1;
        ob[(size_t)(rbase + 2) * DIM + col] = acc[dt][2] * i2;
        ob[(size_t)(rbase + 3) * DIM + col] = acc[dt][3] * i3;
    }
}

extern "C" void kernel_launch(void* const* d_in, const int* in_sizes, int n_in,
                              void* d_out, int out_size, void* d_ws, size_t ws_size,
                              hipStream_t stream) {
    const float* q = (const float*)d_in[0];
    const float* k = (const float*)d_in[1];
    const float* v = (const float*)d_in[2];
    const int* valid_lens = (const int*)d_in[3];
    float* out = (float*)d_out;

    if (d_ws != nullptr && ws_size >= WS_NEEDED) {
        float2* lmbuf = (float2*)d_ws;
        float*  opart = (float*)((char*)d_ws + WS_O_OFF);
        attn_mfma_splitk<<<dim3(BATCH * (SEQ / BQ) * 2), dim3(256), 0, stream>>>(
            q, k, v, valid_lens, out, lmbuf, opart);
        attn_combine<<<dim3(BATCH * (SEQ / BQ)), dim3(256), 0, stream>>>(
            valid_lens, lmbuf, opart, out);
    } else {
        dim3 grid(BATCH * (SEQ / BQ));       // 1024 blocks
        attn_mfma_flash2<<<grid, dim3(256), 0, stream>>>(q, k, v, valid_lens, out);
    }
}